// Round 4
// baseline (206.889 us; speedup 1.0000x reference)
//
#include <hip/hip_runtime.h>
#include <stdint.h>

// Problem: cosine-similarity relations.
//   support: (2,5,1024,128) fp32 -> 10240 rows; query: (2,4,1024,128) -> 8192 rows
//   out: (2,4,5,1024,1024) fp32 = 167.8 MB  -> write-BW-bound (~27 us floor)
// R3 -> R4: occupancy/issue attack. Same no-LDS direct-fragment-load GEMM
// (proven correct), but wave tile 64x64 -> 64x32: acc VGPRs 64 -> 32, live
// frags 8 -> 6, est ~116 -> ~90 VGPR => 4 -> 6 waves/SIMD. 512-thr blocks,
// 8 waves per 128x128 tile. More resident waves = better L2-latency hiding
// and smoother interleave of per-block epilogue write bursts (the kernel's
// floor is the 167.8 MB output stream).

#define S_ROWS 10240
#define Q_ROWS 8192

typedef __attribute__((ext_vector_type(8))) short short8;   // 8 bf16 (4 VGPRs)
typedef __attribute__((ext_vector_type(4))) float floatx4;  // 16x16 MFMA acc

__device__ static inline unsigned short f32_to_bf16_rne(float f) {
    union { float f; uint32_t u; } c; c.f = f;
    uint32_t u = c.u;
    uint32_t r = u + 0x7FFFu + ((u >> 16) & 1u);   // round-to-nearest-even
    return (unsigned short)(r >> 16);
}

// ---------------- Kernel 1: L2-normalize rows of 128, cast to bf16 ----------
__global__ __launch_bounds__(256) void norm_cast_kernel(
    const float* __restrict__ support, const float* __restrict__ query,
    unsigned short* __restrict__ sn, unsigned short* __restrict__ qn)
{
    int wave = blockIdx.x * 4 + (threadIdx.x >> 6);
    int lane = threadIdx.x & 63;

    const float* src;
    unsigned short* dst;
    if (wave < S_ROWS) {
        src = support + (size_t)wave * 128;
        dst = sn + (size_t)wave * 128;
    } else {
        int r = wave - S_ROWS;
        src = query + (size_t)r * 128;
        dst = qn + (size_t)r * 128;
    }

    float2 v = ((const float2*)src)[lane];
    float s = v.x * v.x + v.y * v.y;
    #pragma unroll
    for (int off = 32; off > 0; off >>= 1) s += __shfl_xor(s, off, 64);
    float inv = 1.0f / fmaxf(sqrtf(s), 1e-12f);

    unsigned short lo = f32_to_bf16_rne(v.x * inv);
    unsigned short hi = f32_to_bf16_rne(v.y * inv);
    ((uint32_t*)dst)[lane] = ((uint32_t)hi << 16) | (uint32_t)lo;
}

// ---------------- Kernel 2: batched C = Qn * Sn^T via bf16 MFMA -------------
// 512 threads (8 waves) per 128x128 output tile; each wave owns 64x32
// (4x2 MFMA 16x16 tiles). No LDS: MFMA operand layout for 16x16x32 means
// lane (quad,ml) needs X[row=ml][k=quad*8+j] -> one global dwordx4 per frag.
__global__ __launch_bounds__(512) void gemm_bt_kernel(
    const unsigned short* __restrict__ qn, const unsigned short* __restrict__ sn,
    float* __restrict__ out)
{
    const int tid  = threadIdx.x;
    const int wave = tid >> 6;           // 0..7
    const int lane = tid & 63;

    const int tn = blockIdx.x & 7;
    const int tm = blockIdx.x >> 3;
    const int y   = blockIdx.y;          // 0..39 -> (b,i,j)
    const int b   = y / 20;
    const int rem = y % 20;
    const int i   = rem / 5;
    const int j   = rem % 5;

    const int wm   = (wave >> 2) * 64;   // 0 / 64
    const int wn   = (wave & 3) * 32;    // 0 / 32 / 64 / 96
    const int ml   = lane & 15;
    const int quad = lane >> 4;

    // Per-lane fragment base pointers (ushort units; quad*8 = 16 B k-chunk).
    const unsigned short* pA = qn
        + ((size_t)(b * 4 + i) * 1024 + tm * 128 + wm + ml) * 128 + quad * 8;
    const unsigned short* pB = sn
        + ((size_t)(b * 5 + j) * 1024 + tn * 128 + wn + ml) * 128 + quad * 8;

    floatx4 acc[4][2] = {};

    #pragma unroll
    for (int kb = 0; kb < 4; ++kb) {
        short8 a[4], bf[2];
        #pragma unroll
        for (int mi = 0; mi < 4; ++mi)
            a[mi] = *(const short8*)&pA[mi * 16 * 128 + kb * 32];
        #pragma unroll
        for (int ni = 0; ni < 2; ++ni)
            bf[ni] = *(const short8*)&pB[ni * 16 * 128 + kb * 32];
        #pragma unroll
        for (int mi = 0; mi < 4; ++mi)
            #pragma unroll
            for (int ni = 0; ni < 2; ++ni)
                acc[mi][ni] = __builtin_amdgcn_mfma_f32_16x16x32_bf16(
                    a[mi], bf[ni], acc[mi][ni], 0, 0, 0);
    }

    // Epilogue: C/D layout col=lane&15, row=quad*4+reg (m89/m91-verified).
    // Per store inst, each quad's 16 lanes cover one aligned 64 B line.
    float* gC = out + ((size_t)((b * 4 + i) * 5 + j) << 20)
                    + (size_t)(tm * 128) * 1024 + tn * 128;
    #pragma unroll
    for (int mi = 0; mi < 4; ++mi) {
        #pragma unroll
        for (int r = 0; r < 4; ++r) {
            const int row = wm + mi * 16 + quad * 4 + r;
            float* rowp = gC + (size_t)row * 1024 + wn + ml;
            #pragma unroll
            for (int ni = 0; ni < 2; ++ni)
                rowp[ni * 16] = acc[mi][ni][r];
        }
    }
}

extern "C" void kernel_launch(void* const* d_in, const int* in_sizes, int n_in,
                              void* d_out, int out_size, void* d_ws, size_t ws_size,
                              hipStream_t stream) {
    const float* support = (const float*)d_in[0];   // (2,5,1024,128)
    const float* query   = (const float*)d_in[1];   // (2,4,1024,128)
    unsigned short* sn = (unsigned short*)d_ws;             // 10240*128 bf16
    unsigned short* qn = sn + (size_t)S_ROWS * 128;         //  8192*128 bf16
    float* out = (float*)d_out;

    norm_cast_kernel<<<dim3((S_ROWS + Q_ROWS) / 4), dim3(256), 0, stream>>>(
        support, query, sn, qn);
    gemm_bt_kernel<<<dim3(64, 40), dim3(512), 0, stream>>>(qn, sn, out);
}

// Round 5
// 175.320 us; speedup vs baseline: 1.1801x; 1.1801x over previous
//
#include <hip/hip_runtime.h>
#include <stdint.h>

// Problem: cosine-similarity relations.
//   support: (2,5,1024,128) fp32 -> 10240 rows; query: (2,4,1024,128) -> 8192 rows
//   out: (2,4,5,1024,1024) fp32 = 167.8 MB  -> write-BW-bound (~27 us floor)
// R4 -> R5: back to R1's low-L2-traffic LDS-shared structure (64 KB/block,
// ranking R1 181.9 < R3 190.8 < R4 206.9 tracks per-block global read volume),
// but with the 16-way ds_read_b128 bank conflict removed via an XOR swizzle
// applied on the ds_write side (staging через VGPRs: coalesced dwordx4 global
// loads + ds_write_b128 — NOT global_load_lds, whose lane-permuted-source
// gather aborted in R2). 16B unit (row,c) lives at LDS unit row*16+(c^(row&15));
// write and read patterns are both 2-way bank aliasing = free (m136).

#define S_ROWS 10240
#define Q_ROWS 8192

typedef __attribute__((ext_vector_type(8))) short short8;   // 8 bf16 (4 VGPRs)
typedef __attribute__((ext_vector_type(4))) float floatx4;  // 16x16 MFMA acc
typedef __attribute__((ext_vector_type(4))) unsigned int uint4x;  // 16 B chunk

__device__ static inline unsigned short f32_to_bf16_rne(float f) {
    union { float f; uint32_t u; } c; c.f = f;
    uint32_t u = c.u;
    uint32_t r = u + 0x7FFFu + ((u >> 16) & 1u);   // round-to-nearest-even
    return (unsigned short)(r >> 16);
}

// ---------------- Kernel 1: L2-normalize rows of 128, cast to bf16 ----------
__global__ __launch_bounds__(256) void norm_cast_kernel(
    const float* __restrict__ support, const float* __restrict__ query,
    unsigned short* __restrict__ sn, unsigned short* __restrict__ qn)
{
    int wave = blockIdx.x * 4 + (threadIdx.x >> 6);
    int lane = threadIdx.x & 63;

    const float* src;
    unsigned short* dst;
    if (wave < S_ROWS) {
        src = support + (size_t)wave * 128;
        dst = sn + (size_t)wave * 128;
    } else {
        int r = wave - S_ROWS;
        src = query + (size_t)r * 128;
        dst = qn + (size_t)r * 128;
    }

    float2 v = ((const float2*)src)[lane];
    float s = v.x * v.x + v.y * v.y;
    #pragma unroll
    for (int off = 32; off > 0; off >>= 1) s += __shfl_xor(s, off, 64);
    float inv = 1.0f / fmaxf(sqrtf(s), 1e-12f);

    unsigned short lo = f32_to_bf16_rne(v.x * inv);
    unsigned short hi = f32_to_bf16_rne(v.y * inv);
    ((uint32_t*)dst)[lane] = ((uint32_t)hi << 16) | (uint32_t)lo;
}

// ---------------- Kernel 2: batched C = Qn * Sn^T via bf16 MFMA -------------
// 256 threads (4 waves), 128x128 tile, 64x64 per wave. A/B tiles staged in
// LDS (64 KB) with XOR-swizzled 16B units; conflict-free ds_read_b128.
__global__ __launch_bounds__(256) void gemm_bt_kernel(
    const unsigned short* __restrict__ qn, const unsigned short* __restrict__ sn,
    float* __restrict__ out)
{
    __shared__ unsigned short As[128 * 128];  // 32 KB, swizzled 16B units
    __shared__ unsigned short Bs[128 * 128];  // 32 KB, swizzled 16B units

    const int tid  = threadIdx.x;
    const int wave = tid >> 6;
    const int lane = tid & 63;

    const int tn = blockIdx.x & 7;
    const int tm = blockIdx.x >> 3;
    const int y   = blockIdx.y;          // 0..39 -> (b,i,j)
    const int b   = y / 20;
    const int rem = y % 20;
    const int i   = rem / 5;
    const int j   = rem % 5;

    const unsigned short* gA = qn + (((size_t)(b * 4 + i) * 1024 + tm * 128) * 128);
    const unsigned short* gB = sn + (((size_t)(b * 5 + j) * 1024 + tn * 128) * 128);

    // Stage 2 x 32 KB. Tile = 2048 16B-units; thread t does units t+256*it.
    // Global loads fully coalesced; ds_write address swizzled.
    uint4x ra[8], rb[8];
    #pragma unroll
    for (int it = 0; it < 8; ++it) {
        ra[it] = ((const uint4x*)gA)[it * 256 + tid];
        rb[it] = ((const uint4x*)gB)[it * 256 + tid];
    }
    #pragma unroll
    for (int it = 0; it < 8; ++it) {
        const int u  = it * 256 + tid;
        const int r  = u >> 4;
        const int cl = u & 15;
        const int su = (r << 4) | (cl ^ (r & 15));   // swizzled LDS unit
        *(uint4x*)&As[su * 8] = ra[it];
        *(uint4x*)&Bs[su * 8] = rb[it];
    }

    const int wm   = (wave >> 1) * 64;
    const int wn   = (wave & 1) * 64;
    const int ml   = lane & 15;
    const int quad = lane >> 4;

    floatx4 acc[4][4] = {};

    __syncthreads();

    #pragma unroll
    for (int kb = 0; kb < 4; ++kb) {
        const int c = kb * 4 + quad;     // 16B-unit column (k-chunk) index
        short8 a[4], bf[4];
        #pragma unroll
        for (int mi = 0; mi < 4; ++mi) {
            const int arow = wm + mi * 16 + ml;          // arow & 15 == ml
            a[mi] = *(const short8*)&As[(((arow << 4) | (c ^ ml))) * 8];
        }
        #pragma unroll
        for (int ni = 0; ni < 4; ++ni) {
            const int brow = wn + ni * 16 + ml;
            bf[ni] = *(const short8*)&Bs[(((brow << 4) | (c ^ ml))) * 8];
        }
        #pragma unroll
        for (int mi = 0; mi < 4; ++mi)
            #pragma unroll
            for (int ni = 0; ni < 4; ++ni)
                acc[mi][ni] = __builtin_amdgcn_mfma_f32_16x16x32_bf16(
                    a[mi], bf[ni], acc[mi][ni], 0, 0, 0);
    }

    // Epilogue: C/D layout col=lane&15, row=quad*4+reg (m89/m91-verified).
    float* gC = out + ((size_t)((b * 4 + i) * 5 + j) << 20)
                    + (size_t)(tm * 128) * 1024 + tn * 128;
    #pragma unroll
    for (int mi = 0; mi < 4; ++mi) {
        #pragma unroll
        for (int r = 0; r < 4; ++r) {
            const int row = wm + mi * 16 + quad * 4 + r;
            float* rowp = gC + (size_t)row * 1024 + wn + ml;
            #pragma unroll
            for (int ni = 0; ni < 4; ++ni)
                rowp[ni * 16] = acc[mi][ni][r];
        }
    }
}

extern "C" void kernel_launch(void* const* d_in, const int* in_sizes, int n_in,
                              void* d_out, int out_size, void* d_ws, size_t ws_size,
                              hipStream_t stream) {
    const float* support = (const float*)d_in[0];   // (2,5,1024,128)
    const float* query   = (const float*)d_in[1];   // (2,4,1024,128)
    unsigned short* sn = (unsigned short*)d_ws;             // 10240*128 bf16
    unsigned short* qn = sn + (size_t)S_ROWS * 128;         //  8192*128 bf16
    float* out = (float*)d_out;

    norm_cast_kernel<<<dim3((S_ROWS + Q_ROWS) / 4), dim3(256), 0, stream>>>(
        support, query, sn, qn);
    gemm_bt_kernel<<<dim3(64, 40), dim3(256), 0, stream>>>(qn, sn, out);
}